// Round 1
// baseline (104.995 us; speedup 1.0000x reference)
//
#include <hip/hip_runtime.h>
#include <stdint.h>

#define N_TOT  8192
#define BHALF  4096
#define DDIM   128
#define NSPLIT 8

typedef short bf16x8 __attribute__((ext_vector_type(8)));
typedef float f32x4  __attribute__((ext_vector_type(4)));

__device__ __forceinline__ float ex2(float x) { return __builtin_amdgcn_exp2f(x); }

__device__ __forceinline__ unsigned short f2bf(float f) {
    uint32_t u = __builtin_bit_cast(uint32_t, f);
    u += 0x7fff + ((u >> 16) & 1);            // RNE
    return (unsigned short)(u >> 16);
}

// K1: cast z=[z_i;z_j] to bf16 scaled by sqrt(10*log2e) so that
// MFMA output is directly t = s*log2(e), s = dot/T.
__global__ void k_cast(const float* __restrict__ zi, const float* __restrict__ zj,
                       unsigned short* __restrict__ zb) {
    const float c = 3.798282440185f;          // sqrt(10*1.4426950408889634)
    int t = blockIdx.x * blockDim.x + threadIdx.x;   // 0..262143
    int e = t * 4;
    int row = e >> 7;
    const float* src = (row < BHALF) ? (zi + e) : (zj + (e - BHALF * DDIM));
    float4 v = *reinterpret_cast<const float4*>(src);
    ushort4 o;
    o.x = f2bf(v.x * c); o.y = f2bf(v.y * c);
    o.z = f2bf(v.z * c); o.w = f2bf(v.w * c);
    *reinterpret_cast<ushort4*>(zb + e) = o;
}

// K2: pos[i] = pos[i+B] = 10 * dot(z_i[i], z_j[i]) in fp32. One wave per pair.
__global__ void k_pos(const float* __restrict__ zi, const float* __restrict__ zj,
                      float* __restrict__ pos) {
    int wid  = (blockIdx.x * blockDim.x + threadIdx.x) >> 6;   // 0..4095
    int lane = threadIdx.x & 63;
    const float* a = zi + wid * DDIM;
    const float* b = zj + wid * DDIM;
    float p = a[lane] * b[lane] + a[lane + 64] * b[lane + 64];
    #pragma unroll
    for (int m = 32; m; m >>= 1) p += __shfl_xor(p, m, 64);
    if (lane == 0) { pos[wid] = 10.f * p; pos[wid + BHALF] = 10.f * p; }
}

// K3: streaming online-logsumexp over sim rows.
// Grid 256 = 32 row-blocks x 8 col-splits. Block: 4 waves, wave = 64 rows.
// Wave tile: 64 rows x 16 cols via 4 subtiles of mfma_f32_16x16x32_bf16.
__launch_bounds__(256, 2)
__global__ void k_main(const unsigned short* __restrict__ zb,
                       float* __restrict__ pm, float* __restrict__ pl) {
    __shared__ unsigned short lds[64 * 136];   // 64 cols x (128 + 8 pad) bf16
    const int tid  = threadIdx.x;
    const int w    = tid >> 6, lane = tid & 63;
    const int q    = lane >> 4, ln = lane & 15;
    const int rb   = blockIdx.x >> 3, cs = blockIdx.x & 7;
    const int rowBase = rb * 256 + w * 64;
    const int colBase = cs * 1024;

    // A fragments: 4 row-subtiles x 4 k-chunks, resident all kernel.
    bf16x8 afr[4][4];
    #pragma unroll
    for (int s = 0; s < 4; ++s) {
        const unsigned short* p = zb + (rowBase + s * 16 + ln) * DDIM + q * 8;
        #pragma unroll
        for (int kc = 0; kc < 4; ++kc)
            afr[s][kc] = *reinterpret_cast<const bf16x8*>(p + kc * 32);
    }

    float m[4][4], l[4][4];
    #pragma unroll
    for (int s = 0; s < 4; ++s)
        #pragma unroll
        for (int r = 0; r < 4; ++r) { m[s][r] = -1e38f; l[s][r] = 0.f; }

    for (int ch = 0; ch < 16; ++ch) {
        // stage 64 columns (16 KB + pad) into LDS, coalesced uint4
        #pragma unroll
        for (int it = 0; it < 4; ++it) {
            int idx = it * 256 + tid;
            int col = idx >> 4, part = idx & 15;
            const uint4* g = reinterpret_cast<const uint4*>(
                zb + (colBase + ch * 64 + col) * DDIM + part * 8);
            *reinterpret_cast<uint4*>(&lds[col * 136 + part * 8]) = *g;
        }
        __syncthreads();

        for (int ct = 0; ct < 4; ++ct) {
            bf16x8 bfr[4];
            const unsigned short* bp = &lds[(ct * 16 + ln) * 136 + q * 8];
            #pragma unroll
            for (int kc = 0; kc < 4; ++kc)
                bfr[kc] = *reinterpret_cast<const bf16x8*>(bp + kc * 32);
            const int colTile = colBase + ch * 64 + ct * 16;

            #pragma unroll
            for (int s = 0; s < 4; ++s) {
                f32x4 acc = {0.f, 0.f, 0.f, 0.f};
                #pragma unroll
                for (int kc = 0; kc < 4; ++kc)
                    acc = __builtin_amdgcn_mfma_f32_16x16x32_bf16(
                        afr[s][kc], bfr[kc], acc, 0, 0, 0);
                // diagonal tile: mask col==row with -inf (wave-uniform branch)
                if (colTile == rowBase + s * 16) {
                    #pragma unroll
                    for (int r = 0; r < 4; ++r)
                        if (ln == q * 4 + r) acc[r] = -__builtin_inff();
                }
                #pragma unroll
                for (int r = 0; r < 4; ++r) {
                    float t  = acc[r];          // = s_ij * log2(e)
                    float mo = m[s][r];
                    float mn = fmaxf(mo, t);
                    float pv = ex2(t - mn);
                    float sc = ex2(mo - mn);
                    l[s][r] = l[s][r] * sc + pv;
                    m[s][r] = mn;
                }
            }
        }
        __syncthreads();
    }

    // merge (m,l) across the 16 lanes (same quad) holding each row
    #pragma unroll
    for (int s = 0; s < 4; ++s) {
        #pragma unroll
        for (int r = 0; r < 4; ++r) {
            float mm = m[s][r], ll = l[s][r];
            #pragma unroll
            for (int msk = 1; msk < 16; msk <<= 1) {
                float om = __shfl_xor(mm, msk, 64);
                float ol = __shfl_xor(ll, msk, 64);
                float mn = fmaxf(mm, om);
                ll = ll * ex2(mm - mn) + ol * ex2(om - mn);
                mm = mn;
            }
            if (ln == 0) {
                int row = rowBase + s * 16 + q * 4 + r;
                pm[cs * N_TOT + row] = mm;
                pl[cs * N_TOT + row] = ll;
            }
        }
    }
}

// K4: per-row merge of 8 col-split partials + the extra exp(pos) term
// (pos appears both as logits[:,0] and inside neg), then block-sum.
__global__ void k_finish(const float* __restrict__ pm, const float* __restrict__ pl,
                         const float* __restrict__ pos, float* __restrict__ partial) {
    int row = blockIdx.x * 256 + threadIdx.x;
    float p  = pos[row];
    float tp = p * 1.4426950408889634f;
    float mm[NSPLIT];
    float M = tp;
    #pragma unroll
    for (int j = 0; j < NSPLIT; ++j) {
        mm[j] = pm[j * N_TOT + row];
        M = fmaxf(M, mm[j]);
    }
    float S = ex2(tp - M);
    #pragma unroll
    for (int j = 0; j < NSPLIT; ++j)
        S += pl[j * N_TOT + row] * ex2(mm[j] - M);
    float lse = (M + __log2f(S)) * 0.6931471805599453f;
    float li  = lse - p;
    #pragma unroll
    for (int msk = 32; msk; msk >>= 1) li += __shfl_xor(li, msk, 64);
    __shared__ float red[4];
    if ((threadIdx.x & 63) == 0) red[threadIdx.x >> 6] = li;
    __syncthreads();
    if (threadIdx.x == 0)
        partial[blockIdx.x] = red[0] + red[1] + red[2] + red[3];
}

__global__ void k_sum(const float* __restrict__ partial, float* __restrict__ out) {
    int lane = threadIdx.x & 63;
    float v = (lane < 32) ? partial[lane] : 0.f;
    #pragma unroll
    for (int msk = 32; msk; msk >>= 1) v += __shfl_xor(v, msk, 64);
    if (lane == 0) out[0] = v * (1.f / 8192.f);
}

extern "C" void kernel_launch(void* const* d_in, const int* in_sizes, int n_in,
                              void* d_out, int out_size, void* d_ws, size_t ws_size,
                              hipStream_t stream) {
    const float* zi = (const float*)d_in[0];
    const float* zj = (const float*)d_in[1];
    float* out = (float*)d_out;
    char* ws = (char*)d_ws;

    unsigned short* zb  = (unsigned short*)ws;                       // 2 MB
    float* pos          = (float*)(ws + 2u * 1024 * 1024);           // 32 KB
    float* pm           = (float*)(ws + 2u * 1024 * 1024 + 32 * 1024);
    float* pl           = pm + NSPLIT * N_TOT;                       // 256 KB each
    float* partial      = pl + NSPLIT * N_TOT;                       // 128 B

    hipLaunchKernelGGL(k_cast,   dim3(1024), dim3(256), 0, stream, zi, zj, zb);
    hipLaunchKernelGGL(k_pos,    dim3(1024), dim3(256), 0, stream, zi, zj, pos);
    hipLaunchKernelGGL(k_main,   dim3(256),  dim3(256), 0, stream, zb, pm, pl);
    hipLaunchKernelGGL(k_finish, dim3(32),   dim3(256), 0, stream, pm, pl, pos, partial);
    hipLaunchKernelGGL(k_sum,    dim3(1),    dim3(64),  0, stream, partial, out);
}